// Round 10
// baseline (378.028 us; speedup 1.0000x reference)
//
#include <hip/hip_runtime.h>

// GRU4Rec fused, round 15: SINGLE-KERNEL scan — gi computed in-MFMA,
// proj + P16 deleted.
//
// Ledger:
//  r6  (345us PASS): 1-wave scan 256us + proj ~89us. P [v][g].
//  r7/r8/r13 (FAIL): 4-wave scan wrong; r14 dual-write diagnostic: 4-wave
//        RAN, nonzero, wrong; plus out held 0 at >=1 element (1000.033 =
//        1000 - ref, ref=-0.0327) => unexplained multi-kernel interaction.
//        4-wave arc CLOSED (5 rounds, 0 us banked).
//  r9  (368us): proj TPW 5->1 regressed +22us => proj real cost >=25us.
//  r10/r11 (503us): P re-layout blew scan FETCH 17x (cache-line math).
//  r12 (343.5us PASS, BEST): proj stores coalesced - no delta.
//  r15 (this): GRU identity: a = [W_ih|W_hh] . [x_t; h] as K=128 MFMA
//        (12 tiles x 4 k-slices = 48 MFMA/step, was 24). r/z: gi+gh fused
//        in accumulator (deletes 12 P16 loads + 48 cvts + 16 adds/step);
//        n: gi/gh separate accs (ref: n = tanh(gi_n + r*gh_n)).
//        Emb B-frags = proj's proven construction; raw-f32 prefetch one
//        step ahead. Gate math / LDS transpose / Lmax loop / freeze =
//        r12 proven bytes. Deletes proj kernel + 38MB P16 traffic + launch.
//
// Shapes: B=4096, T=200, H=64, V=100000. Output fp32.

#define T_SEQ 200
#define HD 64

typedef float v4f __attribute__((ext_vector_type(4)));
typedef float v8f __attribute__((ext_vector_type(8)));
typedef _Float16 v8h __attribute__((ext_vector_type(8)));
typedef _Float16 h2 __attribute__((ext_vector_type(2)));
typedef unsigned v2u __attribute__((ext_vector_type(2)));

__device__ __forceinline__ float fsigmoid(float x) {
  float e = __builtin_amdgcn_exp2f(x * -1.442695040888963f);
  return __builtin_amdgcn_rcpf(1.0f + e);
}
__device__ __forceinline__ float ftanh(float x) {
  float e = __builtin_amdgcn_exp2f(x * -2.885390081777927f);
  return fmaf(2.0f, __builtin_amdgcn_rcpf(1.0f + e), -1.0f);
}
__device__ __forceinline__ float hlo(unsigned u) {
  h2 h = __builtin_bit_cast(h2, u);
  return (float)h[0];
}
__device__ __forceinline__ float hhi(unsigned u) {
  h2 h = __builtin_bit_cast(h2, u);
  return (float)h[1];
}
__device__ __forceinline__ unsigned pack_rne(float a, float b) {
  h2 w;
  w[0] = (_Float16)a;
  w[1] = (_Float16)b;
  return __builtin_bit_cast(unsigned, w);
}

// A-fragment of one [16 x 64] f32 row-major weight block (tile tau, K-slice
// kappa) for v_mfma_f32_16x16x32_f16. Lane l holds
// W[16*tau + (l&15)][32*kappa + 8*(l>>4) + j], j=0..7. RNE cvt. (Proven.)
__device__ __forceinline__ v8h load_wfrag(const float* __restrict__ W,
                                          int tau, int kappa, int m, int p) {
  const float* src = W + (size_t)(tau * 16 + m) * HD + kappa * 32 + p * 8;
  v8f f = *reinterpret_cast<const v8f*>(src);
  return __builtin_convertvector(f, v8h);
}

// One wave = 16 sequences (MFMA columns). Lane (m,p) owns h[16tau+4p+q]
// of seq m. Per step:
//   cvt raw emb frags (loaded LAST step) -> f16 B-frags for x_t;
//   prefetch raw emb frags for token t+1 (+ token index t+2);
//   48 MFMA: r/z accs = Ai.x + Ah.h fused; n: gi/gh separate;
//   r12 gate math; fp32 h update; freeze; pack; LDS transpose -> h B-frag.
#define STEPF(XR0, XR1, YR0, YR1)                                             \
  {                                                                           \
    v8h ex0 = __builtin_convertvector(XR0, v8h);                              \
    v8h ex1 = __builtin_convertvector(XR1, v8h);                              \
    int i2_ = (t + 2 < L) ? (t + 2) : 0;                                      \
    int tk2_ = tokp[i2_];                                                     \
    {                                                                         \
      const float* er_ = emb + (size_t)tk1 * HD + p * 8;                      \
      YR0 = *reinterpret_cast<const v8f*>(er_);                               \
      YR1 = *reinterpret_cast<const v8f*>(er_ + 32);                          \
    }                                                                         \
    unsigned pw[4][2];                                                        \
    _Pragma("unroll")                                                         \
    for (int hf = 0; hf < 2; ++hf) {                                          \
      v4f acr[2], acz[2], acni[2], acnh[2];                                   \
      _Pragma("unroll")                                                       \
      for (int tl = 0; tl < 2; ++tl) {                                        \
        const int ta = hf * 2 + tl;                                           \
        v4f a_;                                                               \
        a_ = __builtin_amdgcn_mfma_f32_16x16x32_f16(Ai[ta][0], ex0, zz, 0, 0, 0); \
        a_ = __builtin_amdgcn_mfma_f32_16x16x32_f16(Ai[ta][1], ex1, a_, 0, 0, 0); \
        a_ = __builtin_amdgcn_mfma_f32_16x16x32_f16(Ah[ta][0], Bf0, a_, 0, 0, 0); \
        acr[tl] = __builtin_amdgcn_mfma_f32_16x16x32_f16(Ah[ta][1], Bf1, a_, 0, 0, 0); \
        a_ = __builtin_amdgcn_mfma_f32_16x16x32_f16(Ai[4 + ta][0], ex0, zz, 0, 0, 0); \
        a_ = __builtin_amdgcn_mfma_f32_16x16x32_f16(Ai[4 + ta][1], ex1, a_, 0, 0, 0); \
        a_ = __builtin_amdgcn_mfma_f32_16x16x32_f16(Ah[4 + ta][0], Bf0, a_, 0, 0, 0); \
        acz[tl] = __builtin_amdgcn_mfma_f32_16x16x32_f16(Ah[4 + ta][1], Bf1, a_, 0, 0, 0); \
        a_ = __builtin_amdgcn_mfma_f32_16x16x32_f16(Ai[8 + ta][0], ex0, zz, 0, 0, 0); \
        acni[tl] = __builtin_amdgcn_mfma_f32_16x16x32_f16(Ai[8 + ta][1], ex1, a_, 0, 0, 0); \
        a_ = __builtin_amdgcn_mfma_f32_16x16x32_f16(Ah[8 + ta][0], Bf0, zz, 0, 0, 0); \
        acnh[tl] = __builtin_amdgcn_mfma_f32_16x16x32_f16(Ah[8 + ta][1], Bf1, a_, 0, 0, 0); \
      }                                                                       \
      _Pragma("unroll")                                                       \
      for (int tl = 0; tl < 2; ++tl) {                                        \
        const int tau = hf * 2 + tl;                                          \
        float hn[4];                                                          \
        _Pragma("unroll")                                                     \
        for (int q = 0; q < 4; ++q) {                                         \
          float r_ = fsigmoid(acr[tl][q]);                                    \
          float z_ = fsigmoid(acz[tl][q]);                                    \
          float n_ = ftanh(fmaf(r_, acnh[tl][q], acni[tl][q]));               \
          hn[q] = fmaf(z_, hv[tau][q] - n_, n_);                              \
          hv[tau][q] = hn[q];                                                 \
        }                                                                     \
        pw[tau][0] = pack_rne(hn[0], hn[1]);                                  \
        pw[tau][1] = pack_rne(hn[2], hn[3]);                                  \
      }                                                                       \
    }                                                                         \
    {                                                                         \
      const bool valid_ = (t < L);                                            \
      _Pragma("unroll")                                                       \
      for (int tau = 0; tau < 4; ++tau) {                                     \
        hpk[tau][0] = valid_ ? pw[tau][0] : hpk[tau][0];                      \
        hpk[tau][1] = valid_ ? pw[tau][1] : hpk[tau][1];                      \
        v2u wv_;                                                              \
        wv_[0] = pw[tau][0];                                                  \
        wv_[1] = pw[tau][1];                                                  \
        *reinterpret_cast<v2u*>(&hbuf[m * 80 + tau * 16 + p * 4]) = wv_;      \
      }                                                                       \
    }                                                                         \
    __builtin_amdgcn_wave_barrier();                                          \
    Bf0 = *reinterpret_cast<const v8h*>(&hbuf[m * 80 + p * 8]);               \
    Bf1 = *reinterpret_cast<const v8h*>(&hbuf[m * 80 + 32 + p * 8]);          \
    tk1 = tk2_;                                                               \
  }

__global__ __launch_bounds__(64, 1) void gru_fused(
    const int* __restrict__ seq_token, const int* __restrict__ seq_pos,
    const float* __restrict__ emb, const float* __restrict__ W_ih,
    const float* __restrict__ W_hh, float* __restrict__ out, int B) {
  // [16 seq rows][80 halves] = 160B row stride (r6-proven transpose).
  __shared__ __align__(16) _Float16 hbuf[16 * 80];
  const int l = threadIdx.x;
  const int m = l & 15;
  const int p = l >> 4;
  const int b = blockIdx.x * 16 + m;
  const int bc = (b < B) ? b : 0;

  v8h Ai[12][2], Ah[12][2];
#pragma unroll
  for (int tt = 0; tt < 12; ++tt) {
    Ai[tt][0] = load_wfrag(W_ih, tt, 0, m, p);
    Ai[tt][1] = load_wfrag(W_ih, tt, 1, m, p);
    Ah[tt][0] = load_wfrag(W_hh, tt, 0, m, p);
    Ah[tt][1] = load_wfrag(W_hh, tt, 1, m, p);
  }

  int L;
  {
    int sp = seq_pos[bc];
    sp = sp < 1 ? 1 : (sp > T_SEQ ? T_SEQ : sp);
    L = (b < B) ? sp : 0;
  }
  int Lr = L;
#pragma unroll
  for (int off = 8; off; off >>= 1) {
    int o = __shfl_xor(Lr, off);
    Lr = Lr > o ? Lr : o;
  }
  const int Lmax = __builtin_amdgcn_readfirstlane(Lr);

  const int* tokp = seq_token + (size_t)bc * T_SEQ;

  v8h Bf0 = {0, 0, 0, 0, 0, 0, 0, 0};  // h = 0
  v8h Bf1 = {0, 0, 0, 0, 0, 0, 0, 0};
  float hv[4][4];      // fp32 running h: hv[tau][q] = h[16tau+4p+q], seq m
  unsigned hpk[4][2];  // frozen packed h (output)
#pragma unroll
  for (int tau = 0; tau < 4; ++tau) {
    hv[tau][0] = hv[tau][1] = hv[tau][2] = hv[tau][3] = 0.f;
    hpk[tau][0] = hpk[tau][1] = 0u;
  }

  v8f rA0, rA1, rB0, rB1;  // raw f32 emb fragments (current / next token)
  int tk1;
  {
    const int tk0 = tokp[0];
    const float* er = emb + (size_t)tk0 * HD + p * 8;
    rA0 = *reinterpret_cast<const v8f*>(er);
    rA1 = *reinterpret_cast<const v8f*>(er + 32);
    tk1 = tokp[(1 < L) ? 1 : 0];
  }

  const v4f zz = {0.f, 0.f, 0.f, 0.f};
  int t = 0;
  while (t < Lmax) {
    STEPF(rA0, rA1, rB0, rB1);
    ++t;
    if (t >= Lmax) break;
    STEPF(rB0, rB1, rA0, rA1);
    ++t;
  }

  if (b < B) {
#pragma unroll
    for (int tau = 0; tau < 4; ++tau) {
#pragma unroll
      for (int qh = 0; qh < 2; ++qh) {
        float2 f;
        f.x = hlo(hpk[tau][qh]);
        f.y = hhi(hpk[tau][qh]);
        *reinterpret_cast<float2*>(out + (size_t)b * HD + tau * 16 + p * 4 +
                                   qh * 2) = f;
      }
    }
  }
}

extern "C" void kernel_launch(void* const* d_in, const int* in_sizes, int n_in,
                              void* d_out, int out_size, void* d_ws,
                              size_t ws_size, hipStream_t stream) {
  const int* seq_token = (const int*)d_in[0];   // [B, T] int32
  const int* seq_pos   = (const int*)d_in[1];   // [B] int32
  const float* emb     = (const float*)d_in[2]; // [V, H]
  const float* W_ih    = (const float*)d_in[3]; // [3H, H]
  const float* W_hh    = (const float*)d_in[4]; // [3H, H]
  float* out = (float*)d_out;                   // [B, H] fp32

  const int B = in_sizes[1];                    // 4096

  gru_fused<<<(B + 15) / 16, 64, 0, stream>>>(seq_token, seq_pos, emb, W_ih,
                                              W_hh, out, B);
}